// Round 1
// baseline (995.815 us; speedup 1.0000x reference)
//
#include <hip/hip_runtime.h>
#include <hip/hip_bf16.h>

#define NF 256
#define HW (512 * 512)
#define NIMG 4
#define BM 64
#define BLOCKS_PER_IMG (HW / BM) // 4096

typedef unsigned short u16;
typedef __attribute__((ext_vector_type(8))) short bf16x8v; // 8 bf16 in 4 VGPRs
typedef __attribute__((ext_vector_type(4))) float f32x4;

// round-to-nearest-even f32 -> bf16
__device__ __forceinline__ u16 f2bf(float f) {
    union { float f; unsigned u; } v; v.f = f;
    unsigned u = v.u;
    return (u16)((u + 0x7fffu + ((u >> 16) & 1u)) >> 16);
}

__device__ __forceinline__ float tanh_fast(float x) {
    float e = __expf(2.0f * x);                    // v_mul + v_exp_f32
    return 1.0f - 2.0f * __builtin_amdgcn_rcpf(e + 1.0f);
}

// LDS swizzle: element index for activation tile A[64][256] (bf16),
// XOR row-low-bits into the 8-element (16B) slot index -> conflict-free
// ds_read_b128 for MFMA A-fragments (rows at stride 512B otherwise all
// hit the same bank; r and r+8 alias -> 2-way, which is free).
#define SWZ(p, j) ((p) * NF + ((j) ^ (((p) & 7) << 3)))

// ---------------------------------------------------------------------------
// prep: fold style into b0, convert+transpose W1/W2/W3 -> bf16 Wt[col][k],
// build zero-padded transposed W4 -> bf16 W4t[16][256].
// ---------------------------------------------------------------------------
__global__ void __launch_bounds__(256)
prep_kernel(const float* __restrict__ W0, const float* __restrict__ b0,
            const float* __restrict__ style,
            const float* __restrict__ W1, const float* __restrict__ W2,
            const float* __restrict__ W3, const float* __restrict__ W4,
            u16* __restrict__ Wt, u16* __restrict__ W4t,
            float* __restrict__ b0f)
{
    int t = blockIdx.x * 256 + threadIdx.x;
    if (t < 3 * NF * NF) {
        int l = t / (NF * NF), rem = t % (NF * NF);
        int col = rem / NF, k = rem % NF;
        const float* W = (l == 0) ? W1 : (l == 1) ? W2 : W3;
        Wt[t] = f2bf(W[k * NF + col]);
    } else if (t < 3 * NF * NF + 16 * NF) {
        int r = t - 3 * NF * NF;
        int col = r / NF, k = r % NF;
        W4t[r] = (col < 3) ? f2bf(W4[k * 3 + col]) : (u16)0;
    } else if (t < 3 * NF * NF + 16 * NF + NF) {
        int j = t - (3 * NF * NF + 16 * NF);
        b0f[j] = b0[j] + style[0] * W0[3 * NF + j]
                       + style[1] * W0[4 * NF + j]
                       + style[2] * W0[5 * NF + j];
    }
}

// ---------------------------------------------------------------------------
// one 256->256 layer: A_dst = tanh(A_src @ W + b), per-wave 64x64 tile.
// A/B fragment layout (16x16x32 bf16): A: lane holds row (lane&15),
// k = (lane>>4)*8 + 0..7 ; B: lane holds col (lane&15), same k slice;
// D: col = lane&15, row = (lane>>4)*4 + reg (m89-verified mapping).
// ---------------------------------------------------------------------------
__device__ __forceinline__ void mlp_layer(const u16* Asrc, u16* Adst,
                                          const u16* __restrict__ Wt,
                                          const float* __restrict__ bias,
                                          int lane, int n0)
{
    f32x4 acc[4][4];
#pragma unroll
    for (int mi = 0; mi < 4; ++mi)
#pragma unroll
        for (int ni = 0; ni < 4; ++ni)
            acc[mi][ni] = (f32x4){0.f, 0.f, 0.f, 0.f};

    const int lr = lane & 15;
    const int lk = (lane >> 4) * 8;

#pragma unroll
    for (int ks = 0; ks < 8; ++ks) {
        const int kbase = ks * 32 + lk;
        bf16x8v a[4], b[4];
#pragma unroll
        for (int mi = 0; mi < 4; ++mi) {
            int r = mi * 16 + lr;
            a[mi] = *(const bf16x8v*)&Asrc[r * NF + (kbase ^ ((r & 7) << 3))];
        }
#pragma unroll
        for (int ni = 0; ni < 4; ++ni) {
            int col = n0 + ni * 16 + lr;
            b[ni] = *(const bf16x8v*)&Wt[col * NF + kbase]; // 16B global, L2-hot
        }
#pragma unroll
        for (int mi = 0; mi < 4; ++mi)
#pragma unroll
            for (int ni = 0; ni < 4; ++ni)
                acc[mi][ni] = __builtin_amdgcn_mfma_f32_16x16x32_bf16(
                    a[mi], b[ni], acc[mi][ni], 0, 0, 0);
    }

#pragma unroll
    for (int ni = 0; ni < 4; ++ni) {
        int col = n0 + ni * 16 + lr;
        float bv = bias[col];
#pragma unroll
        for (int mi = 0; mi < 4; ++mi) {
#pragma unroll
            for (int r = 0; r < 4; ++r) {
                int row = mi * 16 + ((lane >> 4) & 3) * 4 + r;
                float v = acc[mi][ni][r] + bv;
                v = tanh_fast(v);
                Adst[SWZ(row, col)] = f2bf(v);
            }
        }
    }
}

// ---------------------------------------------------------------------------
// fused per-pixel MLP: block = 256 threads (4 waves) = 64 pixels.
// ---------------------------------------------------------------------------
__global__ void __launch_bounds__(256, 2)
main_kernel(const float* __restrict__ x, const float* __restrict__ W0,
            const float* __restrict__ b1, const float* __restrict__ b2,
            const float* __restrict__ b3, const float* __restrict__ b4,
            const u16* __restrict__ Wt, const u16* __restrict__ W4t,
            const float* __restrict__ b0f, float* __restrict__ out)
{
    __shared__ __align__(16) u16 A0[BM * NF]; // 32 KB, swizzled bf16
    __shared__ __align__(16) u16 A1[BM * NF]; // 32 KB
    __shared__ float xs[3][BM];               // raw input tile (for residual)

    const int tid  = threadIdx.x;
    const int lane = tid & 63;
    const int wave = tid >> 6;
    const int blk  = blockIdx.x;
    const int img  = blk / BLOCKS_PER_IMG;
    const int idx0 = (blk % BLOCKS_PER_IMG) * BM;
    const size_t xbase = (size_t)img * 3 * HW + idx0;

    if (tid < 192) {
        int c = tid >> 6, p = tid & 63;
        xs[c][p] = x[xbase + (size_t)c * HW + p];
    }
    __syncthreads();

    // ---- layer 0: 3 -> 256, relu (style folded into b0f) --------------------
    {
        int j = tid;
        float w0 = W0[j], w1 = W0[NF + j], w2 = W0[2 * NF + j];
        float bb = b0f[j];
#pragma unroll 8
        for (int p = 0; p < BM; ++p) {
            float h = fmaf(xs[0][p], w0,
                      fmaf(xs[1][p], w1,
                      fmaf(xs[2][p], w2, bb)));
            h = fmaxf(h, 0.0f);
            A0[SWZ(p, j)] = f2bf(h);
        }
    }
    __syncthreads();

    // ---- layers 1..3: 256 -> 256, tanh, MFMA --------------------------------
    const int n0 = wave * 64;
    mlp_layer(A0, A1, Wt,              b1, lane, n0);
    __syncthreads();
    mlp_layer(A1, A0, Wt + NF * NF,    b2, lane, n0);
    __syncthreads();
    mlp_layer(A0, A1, Wt + 2 * NF * NF, b3, lane, n0);
    __syncthreads();

    // ---- final layer: 256 -> 3 (16-padded MFMA), residual + clip ------------
    {
        const int lr = lane & 15;
        const int lk = (lane >> 4) * 8;
        const int m0 = wave * 16; // each wave: 16 pixels
        f32x4 accf = (f32x4){0.f, 0.f, 0.f, 0.f};
#pragma unroll
        for (int ks = 0; ks < 8; ++ks) {
            int kbase = ks * 32 + lk;
            int r = m0 + lr;
            bf16x8v a = *(const bf16x8v*)&A1[r * NF + (kbase ^ ((r & 7) << 3))];
            bf16x8v b = *(const bf16x8v*)&W4t[lr * NF + kbase];
            accf = __builtin_amdgcn_mfma_f32_16x16x32_bf16(a, b, accf, 0, 0, 0);
        }
        if (lr < 3) { // cols 0..2 are the real output channels
            float bv = b4[lr];
#pragma unroll
            for (int rr = 0; rr < 4; ++rr) {
                int p = m0 + ((lane >> 4) & 3) * 4 + rr;
                float v = accf[rr] + bv + xs[lr][p];
                v = fminf(fmaxf(v, 0.0f), 1.0f);
                out[xbase + (size_t)lr * HW + p] = v;
            }
        }
    }
}

extern "C" void kernel_launch(void* const* d_in, const int* in_sizes, int n_in,
                              void* d_out, int out_size, void* d_ws, size_t ws_size,
                              hipStream_t stream) {
    const float* x     = (const float*)d_in[0];
    const float* style = (const float*)d_in[1];
    const float* W0    = (const float*)d_in[2];
    const float* b0    = (const float*)d_in[3];
    const float* W1    = (const float*)d_in[4];
    const float* b1    = (const float*)d_in[5];
    const float* W2    = (const float*)d_in[6];
    const float* b2    = (const float*)d_in[7];
    const float* W3    = (const float*)d_in[8];
    const float* b3    = (const float*)d_in[9];
    const float* W4    = (const float*)d_in[10];
    const float* b4    = (const float*)d_in[11];
    float* out = (float*)d_out;

    // ws layout: Wt (3*256*256 bf16) | W4t (16*256 bf16) | b0f (256 f32)
    u16*   Wt  = (u16*)d_ws;
    u16*   W4t = Wt + 3 * NF * NF;
    float* b0f = (float*)(W4t + 16 * NF);

    const int prep_threads = 3 * NF * NF + 16 * NF + NF; // 200960
    prep_kernel<<<(prep_threads + 255) / 256, 256, 0, stream>>>(
        W0, b0, style, W1, W2, W3, W4, Wt, W4t, b0f);

    main_kernel<<<NIMG * BLOCKS_PER_IMG, 256, 0, stream>>>(
        x, W0, b1, b2, b3, b4, Wt, W4t, b0f, out);
}

// Round 2
// 965.276 us; speedup vs baseline: 1.0316x; 1.0316x over previous
//
#include <hip/hip_runtime.h>
#include <hip/hip_bf16.h>

#define NF 256
#define HW (512 * 512)
#define NIMG 4
#define BM 64
#define BLOCKS_PER_IMG (HW / BM) // 4096

typedef unsigned short u16;
typedef unsigned int u32;
typedef __attribute__((ext_vector_type(8))) short bf16x8v; // 8 bf16 in 4 VGPRs
typedef __attribute__((ext_vector_type(4))) float f32x4;
typedef __attribute__((ext_vector_type(4))) unsigned int u32x4;
typedef __attribute__((ext_vector_type(2))) unsigned int u32x2;

// round-to-nearest-even f32 -> bf16 (prep only)
__device__ __forceinline__ u16 f2bf(float f) {
    union { float f; unsigned u; } v; v.f = f;
    unsigned u = v.u;
    return (u16)((u + 0x7fffu + ((u >> 16) & 1u)) >> 16);
}

// packed f32x2 -> bf16x2 (RNE), single VALU instr
__device__ __forceinline__ u32 cvt_pk(float lo, float hi) {
    u32 r;
    asm("v_cvt_pk_bf16_f32 %0, %1, %2" : "=v"(r) : "v"(lo), "v"(hi));
    return r;
}

// tanh(x) = 1 - 2/(e^2x + 1); e^2x via single v_exp_f32 (2^(x*2log2e))
__device__ __forceinline__ float tanh_fast(float x) {
    float e = __builtin_amdgcn_exp2f(x * 2.8853900817779268f);
    return fmaf(-2.0f, __builtin_amdgcn_rcpf(e + 1.0f), 1.0f);
}

// LDS swizzle on activation tile A[64 pixels][256 feats] bf16: XOR pixel-low
// bits into the 8-elem (16B) slot index. Rows are 512B apart (bank-0 aligned);
// the XOR spreads lanes across banks; residual 2-way aliasing (p vs p+8) is free.
#define SWZ(p, j) ((p) * NF + ((j) ^ (((p) & 7) << 3)))

// ---------------------------------------------------------------------------
// prep: fold style into b0, convert+transpose W1/W2/W3 -> bf16 Wt[j_out][k],
// zero-padded transposed W4 -> bf16 W4t[16][256].
// ---------------------------------------------------------------------------
__global__ void __launch_bounds__(256)
prep_kernel(const float* __restrict__ W0, const float* __restrict__ b0,
            const float* __restrict__ style,
            const float* __restrict__ W1, const float* __restrict__ W2,
            const float* __restrict__ W3, const float* __restrict__ W4,
            u16* __restrict__ Wt, u16* __restrict__ W4t,
            float* __restrict__ b0f)
{
    int t = blockIdx.x * 256 + threadIdx.x;
    if (t < 3 * NF * NF) {
        int l = t / (NF * NF), rem = t % (NF * NF);
        int col = rem / NF, k = rem % NF;
        const float* W = (l == 0) ? W1 : (l == 1) ? W2 : W3;
        Wt[t] = f2bf(W[k * NF + col]);
    } else if (t < 3 * NF * NF + 16 * NF) {
        int r = t - 3 * NF * NF;
        int col = r / NF, k = r % NF;
        W4t[r] = (col < 3) ? f2bf(W4[k * 3 + col]) : (u16)0;
    } else if (t < 3 * NF * NF + 16 * NF + NF) {
        int j = t - (3 * NF * NF + 16 * NF);
        b0f[j] = b0[j] + style[0] * W0[3 * NF + j]
                       + style[1] * W0[4 * NF + j]
                       + style[2] * W0[5 * NF + j];
    }
}

// ---------------------------------------------------------------------------
// one 256->256 layer with SWAPPED MFMA operands:
//   D^T[j][p] = sum_k W^T[j][k] * Act^T[k][p]
// A-op (W): lane row = out-feature j = wslice + mi*16 + (lane&15), k = 32ks+8h+r
// B-op (X): lane col = pixel p = ni*16 + (lane&15),   k = 32ks+8h+r (LDS, swz)
// D: col = pixel = lane&15, row = j = 4h + reg  -> lane holds 4 CONSECUTIVE
// features of one pixel -> cvt_pk pairs -> one ds_write_b64 per fragment.
// In-place update of A: [MFMA reads] barrier [tanh+pack+write]; caller
// barriers again before the next layer's reads.
// ---------------------------------------------------------------------------
__device__ __forceinline__ void mlp_layer(u16* A, const u16* __restrict__ Wt,
                                          const float* __restrict__ bias,
                                          int lane, int wave)
{
    const int lr = lane & 15;
    const int h  = lane >> 4;

    f32x4 acc[4][4]; // [mi: feature-frag][ni: pixel-frag]
#pragma unroll
    for (int mi = 0; mi < 4; ++mi)
#pragma unroll
        for (int ni = 0; ni < 4; ++ni)
            acc[mi][ni] = (f32x4){0.f, 0.f, 0.f, 0.f};

    const u16* wbase = Wt + (wave * 64 + lr) * NF;

#pragma unroll
    for (int ks = 0; ks < 8; ++ks) {
        const int kb = ks * 32 + h * 8;
        bf16x8v w[4], act[4];
#pragma unroll
        for (int mi = 0; mi < 4; ++mi)
            w[mi] = *(const bf16x8v*)(wbase + mi * 16 * NF + kb);
#pragma unroll
        for (int ni = 0; ni < 4; ++ni) {
            int p = ni * 16 + lr;
            act[ni] = *(const bf16x8v*)&A[p * NF + (kb ^ ((p & 7) << 3))];
        }
#pragma unroll
        for (int mi = 0; mi < 4; ++mi)
#pragma unroll
            for (int ni = 0; ni < 4; ++ni)
                acc[mi][ni] = __builtin_amdgcn_mfma_f32_16x16x32_bf16(
                    w[mi], act[ni], acc[mi][ni], 0, 0, 0);
    }

    __syncthreads(); // all waves done READING A; safe to overwrite

#pragma unroll
    for (int mi = 0; mi < 4; ++mi) {
        const int j0 = wave * 64 + mi * 16 + h * 4; // 4 consecutive features
        const f32x4 bv = *(const f32x4*)&bias[j0];
#pragma unroll
        for (int ni = 0; ni < 4; ++ni) {
            int p = ni * 16 + lr;
            float v0 = tanh_fast(acc[mi][ni][0] + bv[0]);
            float v1 = tanh_fast(acc[mi][ni][1] + bv[1]);
            float v2 = tanh_fast(acc[mi][ni][2] + bv[2]);
            float v3 = tanh_fast(acc[mi][ni][3] + bv[3]);
            u32x2 pk = (u32x2){cvt_pk(v0, v1), cvt_pk(v2, v3)};
            *(u32x2*)&A[SWZ(p, j0)] = pk; // 8B-aligned (swz flips bits 3..5 only)
        }
    }
}

// ---------------------------------------------------------------------------
// fused per-pixel MLP: block = 256 threads (4 waves) = 64 pixels, 32 KB LDS.
// ---------------------------------------------------------------------------
__global__ void __launch_bounds__(256, 4)
main_kernel(const float* __restrict__ x, const float* __restrict__ W0,
            const float* __restrict__ b1, const float* __restrict__ b2,
            const float* __restrict__ b3, const float* __restrict__ b4,
            const u16* __restrict__ Wt, const u16* __restrict__ W4t,
            const float* __restrict__ b0f, float* __restrict__ out)
{
    __shared__ __align__(16) u16 A[BM * NF]; // 32 KB exactly -> 4 blocks/CU

    const int tid  = threadIdx.x;
    const int lane = tid & 63;
    const int wave = tid >> 6;
    const int blk  = blockIdx.x;
    const int img  = blk >> 12;            // / 4096
    const int idx0 = (blk & 4095) * BM;
    const size_t xbase = (size_t)img * 3 * HW + idx0;

    // ---- layer 0: 3 -> 256, relu (style folded into b0f). Pixel-major:
    // thread (p = tid&63, g = tid>>6) computes features [64g, 64g+64) of
    // pixel p -> packed b128 LDS writes (8 feats = one 16B swizzle slot).
    {
        const int p = tid & 63;
        const int g = tid >> 6;
        float x0 = x[xbase + p];
        float x1 = x[xbase + HW + p];
        float x2 = x[xbase + 2 * HW + p];
#pragma unroll
        for (int c8 = 0; c8 < 8; ++c8) {
            const int j0 = g * 64 + c8 * 8;
            u32 pk[4];
#pragma unroll
            for (int jj = 0; jj < 8; jj += 2) {
                int j = j0 + jj;
                float va = fmaf(x0, W0[j],     fmaf(x1, W0[NF + j],     fmaf(x2, W0[2 * NF + j],     b0f[j])));
                float vb = fmaf(x0, W0[j + 1], fmaf(x1, W0[NF + j + 1], fmaf(x2, W0[2 * NF + j + 1], b0f[j + 1])));
                pk[jj >> 1] = cvt_pk(fmaxf(va, 0.f), fmaxf(vb, 0.f));
            }
            *(u32x4*)&A[SWZ(p, j0)] = (u32x4){pk[0], pk[1], pk[2], pk[3]};
        }
    }
    __syncthreads();

    // ---- layers 1..3: 256 -> 256, tanh, in-place, 2 barriers each ----------
    mlp_layer(A, Wt,              b1, lane, wave);
    __syncthreads();
    mlp_layer(A, Wt + NF * NF,    b2, lane, wave);
    __syncthreads();
    mlp_layer(A, Wt + 2 * NF * NF, b3, lane, wave);
    __syncthreads();

    // ---- final layer: 256 -> 3 (16-padded, swapped), residual + clip -------
    {
        const int lr = lane & 15;
        const int h  = lane >> 6 ? 0 : (lane >> 4); // (lane>>4) in 0..3
        const int hh = lane >> 4;
        const int p  = wave * 16 + lr; // each wave: 16 pixels
        f32x4 accf = (f32x4){0.f, 0.f, 0.f, 0.f};
#pragma unroll
        for (int ks = 0; ks < 8; ++ks) {
            int kb = ks * 32 + hh * 8;
            bf16x8v w = *(const bf16x8v*)&W4t[lr * NF + kb]; // row = channel
            bf16x8v a = *(const bf16x8v*)&A[p * NF + (kb ^ ((p & 7) << 3))];
            accf = __builtin_amdgcn_mfma_f32_16x16x32_bf16(w, a, accf, 0, 0, 0);
        }
        (void)h;
        if (hh == 0) { // D rows 0..3 = channels; rows live in lanes h==0
#pragma unroll
            for (int c = 0; c < 3; ++c) {
                float v = accf[c] + b4[c] + x[xbase + (size_t)c * HW + p];
                v = fminf(fmaxf(v, 0.0f), 1.0f);
                out[xbase + (size_t)c * HW + p] = v;
            }
        }
    }
}

extern "C" void kernel_launch(void* const* d_in, const int* in_sizes, int n_in,
                              void* d_out, int out_size, void* d_ws, size_t ws_size,
                              hipStream_t stream) {
    const float* x     = (const float*)d_in[0];
    const float* style = (const float*)d_in[1];
    const float* W0    = (const float*)d_in[2];
    const float* b0    = (const float*)d_in[3];
    const float* W1    = (const float*)d_in[4];
    const float* b1    = (const float*)d_in[5];
    const float* W2    = (const float*)d_in[6];
    const float* b2    = (const float*)d_in[7];
    const float* W3    = (const float*)d_in[8];
    const float* b3    = (const float*)d_in[9];
    const float* W4    = (const float*)d_in[10];
    const float* b4    = (const float*)d_in[11];
    float* out = (float*)d_out;

    // ws layout: Wt (3*256*256 bf16) | W4t (16*256 bf16) | b0f (256 f32)
    u16*   Wt  = (u16*)d_ws;
    u16*   W4t = Wt + 3 * NF * NF;
    float* b0f = (float*)(W4t + 16 * NF);

    const int prep_threads = 3 * NF * NF + 16 * NF + NF;
    prep_kernel<<<(prep_threads + 255) / 256, 256, 0, stream>>>(
        W0, b0, style, W1, W2, W3, W4, Wt, W4t, b0f);

    main_kernel<<<NIMG * BLOCKS_PER_IMG, 256, 0, stream>>>(
        x, W0, b1, b2, b3, b4, Wt, W4t, b0f, out);
}

// Round 3
// 605.422 us; speedup vs baseline: 1.6448x; 1.5944x over previous
//
#include <hip/hip_runtime.h>
#include <hip/hip_bf16.h>

#define NF 256
#define HW (512 * 512)
#define NIMG 4
#define BM 64
#define BLOCKS_PER_IMG (HW / BM) // 4096

typedef unsigned short u16;
typedef unsigned int u32;
typedef __attribute__((ext_vector_type(8))) short bf16x8v; // 8 bf16 in 4 VGPRs
typedef __attribute__((ext_vector_type(4))) float f32x4;
typedef __attribute__((ext_vector_type(4))) unsigned int u32x4;
typedef __attribute__((ext_vector_type(2))) unsigned int u32x2;

// round-to-nearest-even f32 -> bf16 (prep only)
__device__ __forceinline__ u16 f2bf(float f) {
    union { float f; unsigned u; } v; v.f = f;
    unsigned u = v.u;
    return (u16)((u + 0x7fffu + ((u >> 16) & 1u)) >> 16);
}

// packed f32x2 -> bf16x2 (RNE), single VALU instr
__device__ __forceinline__ u32 cvt_pk(float lo, float hi) {
    u32 r;
    asm("v_cvt_pk_bf16_f32 %0, %1, %2" : "=v"(r) : "v"(lo), "v"(hi));
    return r;
}

// tanh(x) = 1 - 2/(e^2x + 1); e^2x via single v_exp_f32
__device__ __forceinline__ float tanh_fast(float x) {
    float e = __builtin_amdgcn_exp2f(x * 2.8853900817779268f);
    return fmaf(-2.0f, __builtin_amdgcn_rcpf(e + 1.0f), 1.0f);
}

// LDS swizzle on activation tile A[64 pixels][256 feats] bf16 (rows 512B apart
// = bank-0 aligned): XOR pixel-low bits into the 16B slot index.
#define SWZ(p, j) ((p) * NF + ((j) ^ (((p) & 7) << 3)))

// Weight fragment layout (coalesced): for layer L, wave-slice w, ks, mi:
//   frag[lane][e]  (64 lanes x 8 bf16 = 1KB contiguous)
//   lane l = 16h + lr holds row (w*64 + mi*16 + lr), k = ks*32 + h*8 + e.
// flat idx = ((((L*4 + w)*8 + ks)*4 + mi)*64 + l)*8 + e
#define WSLICE_STRIDE (8 * 4 * 64 * 8) // 16384 elems per (L,w)

// ---------------------------------------------------------------------------
// prep: fold style into b0; emit fragment-ordered bf16 Wt (3 layers) and W4t.
// ---------------------------------------------------------------------------
__global__ void __launch_bounds__(256)
prep_kernel(const float* __restrict__ W0, const float* __restrict__ b0,
            const float* __restrict__ style,
            const float* __restrict__ W1, const float* __restrict__ W2,
            const float* __restrict__ W3, const float* __restrict__ W4,
            u16* __restrict__ Wt, u16* __restrict__ W4t,
            float* __restrict__ b0f)
{
    int t = blockIdx.x * 256 + threadIdx.x;
    if (t < 3 * NF * NF) {
        int e  = t & 7;
        int l  = (t >> 3) & 63;
        int mi = (t >> 9) & 3;
        int ks = (t >> 11) & 7;
        int w  = (t >> 14) & 3;
        int L  = t >> 16;
        const float* W = (L == 0) ? W1 : (L == 1) ? W2 : W3;
        int row = w * 64 + mi * 16 + (l & 15);
        int k   = ks * 32 + (l >> 4) * 8 + e;
        Wt[t] = f2bf(W[k * NF + row]);
    } else if (t < 3 * NF * NF + 16 * NF) {
        int r  = t - 3 * NF * NF;      // 4096 elems: [ks][lane][e]
        int e  = r & 7;
        int l  = (r >> 3) & 63;
        int ks = r >> 9;
        int row = l & 15;              // output channel (0..2) or zero-pad
        int k   = ks * 32 + (l >> 4) * 8 + e;
        W4t[r] = (row < 3) ? f2bf(W4[k * 3 + row]) : (u16)0;
    } else if (t < 3 * NF * NF + 16 * NF + NF) {
        int j = t - (3 * NF * NF + 16 * NF);
        b0f[j] = b0[j] + style[0] * W0[3 * NF + j]
                       + style[1] * W0[4 * NF + j]
                       + style[2] * W0[5 * NF + j];
    }
}

// ---------------------------------------------------------------------------
// one 256->256 layer, swapped MFMA operands:
//   A-op = W fragment (coalesced global, L2-hot), B-op = activations (LDS).
// D: col = pixel = lane&15, row = feature = h*4 + reg -> lane holds 4
// consecutive features of one pixel -> cvt_pk pairs -> ds_write_b64.
// ---------------------------------------------------------------------------
__device__ __forceinline__ void mlp_layer(u16* A, const u16* __restrict__ Wslice,
                                          const float* __restrict__ bias,
                                          int lane, int wave)
{
    const int lr = lane & 15;
    const int h  = lane >> 4;

    f32x4 acc[4][4]; // [mi: feature-frag][ni: pixel-frag]
#pragma unroll
    for (int mi = 0; mi < 4; ++mi)
#pragma unroll
        for (int ni = 0; ni < 4; ++ni)
            acc[mi][ni] = (f32x4){0.f, 0.f, 0.f, 0.f};

#pragma unroll
    for (int ks = 0; ks < 8; ++ks) {
        const int kb = ks * 32 + h * 8;
        bf16x8v w[4], act[4];
#pragma unroll
        for (int mi = 0; mi < 4; ++mi)
            w[mi] = *(const bf16x8v*)(Wslice + ((ks * 4 + mi) * 64 + lane) * 8);
#pragma unroll
        for (int ni = 0; ni < 4; ++ni) {
            int p = ni * 16 + lr;
            act[ni] = *(const bf16x8v*)&A[p * NF + (kb ^ ((p & 7) << 3))];
        }
#pragma unroll
        for (int mi = 0; mi < 4; ++mi)
#pragma unroll
            for (int ni = 0; ni < 4; ++ni)
                acc[mi][ni] = __builtin_amdgcn_mfma_f32_16x16x32_bf16(
                    w[mi], act[ni], acc[mi][ni], 0, 0, 0);
    }

    __syncthreads(); // all waves done READING A; safe to overwrite

#pragma unroll
    for (int mi = 0; mi < 4; ++mi) {
        const int j0 = wave * 64 + mi * 16 + h * 4; // 4 consecutive features
        const f32x4 bv = *(const f32x4*)&bias[j0];
#pragma unroll
        for (int ni = 0; ni < 4; ++ni) {
            int p = ni * 16 + lr;
            float v0 = tanh_fast(acc[mi][ni][0] + bv[0]);
            float v1 = tanh_fast(acc[mi][ni][1] + bv[1]);
            float v2 = tanh_fast(acc[mi][ni][2] + bv[2]);
            float v3 = tanh_fast(acc[mi][ni][3] + bv[3]);
            u32x2 pk = (u32x2){cvt_pk(v0, v1), cvt_pk(v2, v3)};
            *(u32x2*)&A[SWZ(p, j0)] = pk; // 8B-aligned (swz flips elem bits 3..5)
        }
    }
}

// ---------------------------------------------------------------------------
// fused per-pixel MLP: block = 256 threads (4 waves) = 64 pixels, 32 KB LDS.
// ---------------------------------------------------------------------------
__global__ void __launch_bounds__(256, 4)
main_kernel(const float* __restrict__ x, const float* __restrict__ W0,
            const float* __restrict__ b1, const float* __restrict__ b2,
            const float* __restrict__ b3, const float* __restrict__ b4,
            const u16* __restrict__ Wt, const u16* __restrict__ W4t,
            const float* __restrict__ b0f, float* __restrict__ out)
{
    __shared__ __align__(16) u16 A[BM * NF]; // 32 KB exactly -> 4 blocks/CU

    const int tid  = threadIdx.x;
    const int lane = tid & 63;
    const int wave = tid >> 6;
    const int blk  = blockIdx.x;
    const int img  = blk >> 12;            // / 4096
    const int idx0 = (blk & 4095) * BM;
    const size_t xbase = (size_t)img * 3 * HW + idx0;

    // ---- layer 0: 3 -> 256, relu (style folded into b0f) --------------------
    {
        const int p = tid & 63;
        const int g = tid >> 6;
        float x0 = x[xbase + p];
        float x1 = x[xbase + HW + p];
        float x2 = x[xbase + 2 * HW + p];
#pragma unroll
        for (int c8 = 0; c8 < 8; ++c8) {
            const int j0 = g * 64 + c8 * 8;
            u32 pk[4];
#pragma unroll
            for (int jj = 0; jj < 8; jj += 2) {
                int j = j0 + jj;
                float va = fmaf(x0, W0[j],     fmaf(x1, W0[NF + j],     fmaf(x2, W0[2 * NF + j],     b0f[j])));
                float vb = fmaf(x0, W0[j + 1], fmaf(x1, W0[NF + j + 1], fmaf(x2, W0[2 * NF + j + 1], b0f[j + 1])));
                pk[jj >> 1] = cvt_pk(fmaxf(va, 0.f), fmaxf(vb, 0.f));
            }
            *(u32x4*)&A[SWZ(p, j0)] = (u32x4){pk[0], pk[1], pk[2], pk[3]};
        }
    }
    __syncthreads();

    // ---- layers 1..3: 256 -> 256, tanh, in-place, 2 barriers each ----------
    const u16* Wsl = Wt + wave * WSLICE_STRIDE;
    mlp_layer(A, Wsl,                       b1, lane, wave);
    __syncthreads();
    mlp_layer(A, Wsl + 4 * WSLICE_STRIDE,   b2, lane, wave);
    __syncthreads();
    mlp_layer(A, Wsl + 8 * WSLICE_STRIDE,   b3, lane, wave);
    __syncthreads();

    // ---- final layer: 256 -> 3 (16-padded, swapped), residual + clip -------
    {
        const int lr = lane & 15;
        const int hh = lane >> 4;
        const int p  = wave * 16 + lr; // each wave: 16 pixels
        f32x4 accf = (f32x4){0.f, 0.f, 0.f, 0.f};
#pragma unroll
        for (int ks = 0; ks < 8; ++ks) {
            int kb = ks * 32 + hh * 8;
            bf16x8v w = *(const bf16x8v*)(W4t + (ks * 64 + lane) * 8);
            bf16x8v a = *(const bf16x8v*)&A[p * NF + (kb ^ ((p & 7) << 3))];
            accf = __builtin_amdgcn_mfma_f32_16x16x32_bf16(w, a, accf, 0, 0, 0);
        }
        if (hh == 0) { // D rows 0..3 = output channels
#pragma unroll
            for (int c = 0; c < 3; ++c) {
                float v = accf[c] + b4[c] + x[xbase + (size_t)c * HW + p];
                v = fminf(fmaxf(v, 0.0f), 1.0f);
                out[xbase + (size_t)c * HW + p] = v;
            }
        }
    }
}

extern "C" void kernel_launch(void* const* d_in, const int* in_sizes, int n_in,
                              void* d_out, int out_size, void* d_ws, size_t ws_size,
                              hipStream_t stream) {
    const float* x     = (const float*)d_in[0];
    const float* style = (const float*)d_in[1];
    const float* W0    = (const float*)d_in[2];
    const float* b0    = (const float*)d_in[3];
    const float* W1    = (const float*)d_in[4];
    const float* b1    = (const float*)d_in[5];
    const float* W2    = (const float*)d_in[6];
    const float* b2    = (const float*)d_in[7];
    const float* W3    = (const float*)d_in[8];
    const float* b3    = (const float*)d_in[9];
    const float* W4    = (const float*)d_in[10];
    const float* b4    = (const float*)d_in[11];
    float* out = (float*)d_out;

    // ws layout: Wt (3*256*256 bf16, fragment-ordered) | W4t (16*256 bf16) | b0f
    u16*   Wt  = (u16*)d_ws;
    u16*   W4t = Wt + 3 * NF * NF;
    float* b0f = (float*)(W4t + 16 * NF);

    const int prep_threads = 3 * NF * NF + 16 * NF + NF;
    prep_kernel<<<(prep_threads + 255) / 256, 256, 0, stream>>>(
        W0, b0, style, W1, W2, W3, W4, Wt, W4t, b0f);

    main_kernel<<<NIMG * BLOCKS_PER_IMG, 256, 0, stream>>>(
        x, W0, b1, b2, b3, b4, Wt, W4t, b0f, out);
}

// Round 5
// 547.728 us; speedup vs baseline: 1.8181x; 1.1053x over previous
//
#include <hip/hip_runtime.h>
#include <hip/hip_bf16.h>

#define NF 256
#define HW (512 * 512)
#define NIMG 4
#define BM 128
#define BLOCKS_PER_IMG (HW / BM) // 2048

typedef unsigned short u16;
typedef unsigned int u32;
typedef __attribute__((ext_vector_type(8))) short bf16x8v; // 8 bf16 in 4 VGPRs
typedef __attribute__((ext_vector_type(4))) float f32x4;
typedef __attribute__((ext_vector_type(4))) unsigned int u32x4;
typedef __attribute__((ext_vector_type(2))) unsigned int u32x2;

// round-to-nearest-even f32 -> bf16 (prep only)
__device__ __forceinline__ u16 f2bf(float f) {
    union { float f; unsigned u; } v; v.f = f;
    unsigned u = v.u;
    return (u16)((u + 0x7fffu + ((u >> 16) & 1u)) >> 16);
}

// packed f32x2 -> bf16x2 (RNE), single VALU instr
__device__ __forceinline__ u32 cvt_pk(float lo, float hi) {
    u32 r;
    asm("v_cvt_pk_bf16_f32 %0, %1, %2" : "=v"(r) : "v"(lo), "v"(hi));
    return r;
}

// tanh(x) = 1 - 2/(e^2x + 1); e^2x via one v_exp_f32 + one v_rcp_f32
__device__ __forceinline__ float tanh_fast(float x) {
    float e = __builtin_amdgcn_exp2f(x * 2.8853900817779268f);
    return fmaf(-2.0f, __builtin_amdgcn_rcpf(e + 1.0f), 1.0f);
}

// LDS swizzle on activation tile A[BM pixels][256 feats] bf16 (rows 512B apart
// = bank-0 aligned): XOR pixel-low bits into the 16B slot index.
#define SWZ(p, j) ((p) * NF + ((j) ^ (((p) & 7) << 3)))

// Weight fragment layout (coalesced): for layer L, wave-slice w, ks, mi:
//   frag[lane][e]  (64 lanes x 8 bf16 = 1KB contiguous)
//   lane l = 16h + lr holds row (w*64 + mi*16 + lr), k = ks*32 + h*8 + e.
// flat idx = ((((L*4 + w)*8 + ks)*4 + mi)*64 + l)*8 + e
#define WSLICE_STRIDE (8 * 4 * 64 * 8) // 16384 elems per (L,w)

// ---------------------------------------------------------------------------
// prep: fold style into b0; emit fragment-ordered bf16 Wt (3 layers) and W4t.
// ---------------------------------------------------------------------------
__global__ void __launch_bounds__(256)
prep_kernel(const float* __restrict__ W0, const float* __restrict__ b0,
            const float* __restrict__ style,
            const float* __restrict__ W1, const float* __restrict__ W2,
            const float* __restrict__ W3, const float* __restrict__ W4,
            u16* __restrict__ Wt, u16* __restrict__ W4t,
            float* __restrict__ b0f)
{
    int t = blockIdx.x * 256 + threadIdx.x;
    if (t < 3 * NF * NF) {
        int e  = t & 7;
        int l  = (t >> 3) & 63;
        int mi = (t >> 9) & 3;
        int ks = (t >> 11) & 7;
        int w  = (t >> 14) & 3;
        int L  = t >> 16;
        const float* W = (L == 0) ? W1 : (L == 1) ? W2 : W3;
        int row = w * 64 + mi * 16 + (l & 15);
        int k   = ks * 32 + (l >> 4) * 8 + e;
        Wt[t] = f2bf(W[k * NF + row]);
    } else if (t < 3 * NF * NF + 16 * NF) {
        int r  = t - 3 * NF * NF;      // 4096 elems: [ks][lane][e]
        int e  = r & 7;
        int l  = (r >> 3) & 63;
        int ks = r >> 9;
        int row = l & 15;              // output channel (0..2) or zero-pad
        int k   = ks * 32 + (l >> 4) * 8 + e;
        W4t[r] = (row < 3) ? f2bf(W4[k * 3 + row]) : (u16)0;
    } else if (t < 3 * NF * NF + 16 * NF + NF) {
        int j = t - (3 * NF * NF + 16 * NF);
        b0f[j] = b0[j] + style[0] * W0[3 * NF + j]
                       + style[1] * W0[4 * NF + j]
                       + style[2] * W0[5 * NF + j];
    }
}

// ---------------------------------------------------------------------------
// layer 0 (3 -> 256, relu) for one pixel-half; thread (p = half*64 + tid&63,
// g = tid>>6) computes features [64g, 64g+64) of pixel p.
// ---------------------------------------------------------------------------
__device__ __forceinline__ void layer0_half(u16* __restrict__ A,
                                            const float* __restrict__ x,
                                            size_t xbase,
                                            const float* __restrict__ W0,
                                            const float* __restrict__ b0f,
                                            int tid, int half)
{
    const int p = half * 64 + (tid & 63);
    const int g = tid >> 6;
    float x0 = x[xbase + p];
    float x1 = x[xbase + HW + p];
    float x2 = x[xbase + 2 * HW + p];
#pragma unroll
    for (int t8 = 0; t8 < 8; ++t8) {
        const int j0 = g * 64 + t8 * 8;
        u32 pk[4];
#pragma unroll
        for (int jj = 0; jj < 8; jj += 2) {
            int j = j0 + jj;
            float va = fmaf(x0, W0[j],     fmaf(x1, W0[NF + j],     fmaf(x2, W0[2 * NF + j],     b0f[j])));
            float vb = fmaf(x0, W0[j + 1], fmaf(x1, W0[NF + j + 1], fmaf(x2, W0[2 * NF + j + 1], b0f[j + 1])));
            pk[jj >> 1] = cvt_pk(fmaxf(va, 0.f), fmaxf(vb, 0.f));
        }
        *(u32x4*)&A[SWZ(p, j0)] = (u32x4){pk[0], pk[1], pk[2], pk[3]};
    }
}

// ---------------------------------------------------------------------------
// fused pipeline phase: MFMA (layer with weights Wsl, bias in C-init) over
// pixel-half hm into accM, INTERLEAVED with tanh-epilogue of accE into
// pixel-half he. One instruction stream -> matrix pipe and VALU overlap.
// Safety: M reads rows of half hm only; E writes rows of half he only;
// hm != he in all <1,1> calls -> disjoint LDS sets across ALL threads.
// D frag: col = pixel = lane&15, row = feature = h*4 + reg.
// ---------------------------------------------------------------------------
template<int DOM, int DOE>
__device__ __forceinline__ void phase(u16* __restrict__ A,
                                      const u16* __restrict__ Wsl,
                                      const float* __restrict__ bias,
                                      f32x4 accM[4][4], f32x4 accE[4][4],
                                      int hm, int he, int lane, int wave)
{
    const int lr = lane & 15;
    const int h  = lane >> 4;

    if (DOM) {
        const int j0b = wave * 64 + h * 4;
#pragma unroll
        for (int mi = 0; mi < 4; ++mi) {
            f32x4 bv = *(const f32x4*)&bias[j0b + mi * 16]; // bias -> C-init
#pragma unroll
            for (int ni = 0; ni < 4; ++ni) accM[mi][ni] = bv;
        }
    }

#pragma unroll
    for (int ks = 0; ks < 8; ++ks) {
        if (DOM) {
            const int kb = ks * 32 + h * 8;
            bf16x8v w[4], act[4];
#pragma unroll
            for (int mi = 0; mi < 4; ++mi)
                w[mi] = *(const bf16x8v*)(Wsl + ((ks * 4 + mi) * 64 + lane) * 8);
#pragma unroll
            for (int ni = 0; ni < 4; ++ni) {
                int p = hm * 64 + ni * 16 + lr;
                act[ni] = *(const bf16x8v*)&A[p * NF + (kb ^ ((p & 7) << 3))];
            }
#pragma unroll
            for (int mi = 0; mi < 4; ++mi)
#pragma unroll
                for (int ni = 0; ni < 4; ++ni)
                    accM[mi][ni] = __builtin_amdgcn_mfma_f32_16x16x32_bf16(
                        w[mi], act[ni], accM[mi][ni], 0, 0, 0);
        }
        if (DOE) {
            // two epilogue units per ks step: unit u = (mi,ni)
#pragma unroll
            for (int j = 0; j < 2; ++j) {
                const int u  = ks * 2 + j;
                const int mi = u >> 2, ni = u & 3;
                const int p  = he * 64 + ni * 16 + lr;
                const int j0 = wave * 64 + mi * 16 + h * 4;
                f32x4 v = accE[mi][ni]; // bias already inside
                float t0 = tanh_fast(v[0]), t1 = tanh_fast(v[1]);
                float t2 = tanh_fast(v[2]), t3 = tanh_fast(v[3]);
                u32x2 pk = (u32x2){cvt_pk(t0, t1), cvt_pk(t2, t3)};
                *(u32x2*)&A[SWZ(p, j0)] = pk;
            }
        }
    }
}

// ---------------------------------------------------------------------------
// fused per-pixel MLP: block = 256 threads (4 waves) = 128 pixels, 65.5 KB LDS.
// Schedule (1 barrier per phase):
//   L0(h0) | M1(h0)+L0(h1) | M1(h1)+E1(h0) | M2(h0)+E1(h1) | M2(h1)+E2(h0)
//   | M3(h0)+E2(h1) | M3(h1)+E3(h0) | E3(h1) | M4 (reads A, writes Ostage)
//   | store (reads Ostage)
// ---------------------------------------------------------------------------
__global__ void __launch_bounds__(256, 2)
main_kernel(const float* __restrict__ x, const float* __restrict__ W0,
            const float* __restrict__ b1, const float* __restrict__ b2,
            const float* __restrict__ b3, const float* __restrict__ b4,
            const u16* __restrict__ Wt, const u16* __restrict__ W4t,
            const float* __restrict__ b0f, float* __restrict__ out)
{
    __shared__ __align__(16) u16 A[BM * NF];       // 64 KB
    __shared__ __align__(16) float Ostage[3 * BM]; // 1.5 KB — dedicated staging;
                                                   // P8 never writes A (race-free)

    const int tid  = threadIdx.x;
    const int lane = tid & 63;
    const int wave = tid >> 6;
    const int blk  = blockIdx.x;
    const int img  = blk >> 11;            // / 2048
    const int idx0 = (blk & 2047) * BM;
    const size_t xbase = (size_t)img * 3 * HW + idx0;

    const u16* Wsl0 = Wt + wave * WSLICE_STRIDE;
    const u16* Wsl1 = Wsl0 + 4 * WSLICE_STRIDE;
    const u16* Wsl2 = Wsl0 + 8 * WSLICE_STRIDE;

    f32x4 accA[4][4], accB[4][4];

    // P0: layer0 half0
    layer0_half(A, x, xbase, W0, b0f, tid, 0);
    __syncthreads();
    // P1: M1(h0) || layer0 half1
    phase<1, 0>(A, Wsl0, b1, accA, accB, 0, 0, lane, wave);
    layer0_half(A, x, xbase, W0, b0f, tid, 1);
    __syncthreads();
    // P2: M1(h1) || E1(h0)
    phase<1, 1>(A, Wsl0, b1, accB, accA, 1, 0, lane, wave);
    __syncthreads();
    // P3: M2(h0) || E1(h1)
    phase<1, 1>(A, Wsl1, b2, accA, accB, 0, 1, lane, wave);
    __syncthreads();
    // P4: M2(h1) || E2(h0)
    phase<1, 1>(A, Wsl1, b2, accB, accA, 1, 0, lane, wave);
    __syncthreads();
    // P5: M3(h0) || E2(h1)
    phase<1, 1>(A, Wsl2, b3, accA, accB, 0, 1, lane, wave);
    __syncthreads();
    // P6: M3(h1) || E3(h0)
    phase<1, 1>(A, Wsl2, b3, accB, accA, 1, 0, lane, wave);
    __syncthreads();
    // P7: E3(h1)
    phase<0, 1>(A, Wsl2, b3, accA, accB, 0, 1, lane, wave);
    __syncthreads();

    // P8: final layer 256 -> 3 (16-padded, b4 in C-init); A is read-only here,
    // results staged into the dedicated Ostage buffer.
    {
        const int lr = lane & 15;
        const int h  = lane >> 4;
        const float b40 = b4[0], b41 = b4[1], b42 = b4[2];
#pragma unroll
        for (int pg = 0; pg < 2; ++pg) {
            const int p4 = wave * 32 + pg * 16 + lr; // 16 pixels per group
            f32x4 accf = (f32x4){b40, b41, b42, 0.f};
#pragma unroll
            for (int ks = 0; ks < 8; ++ks) {
                int kb = ks * 32 + h * 8;
                bf16x8v w = *(const bf16x8v*)(W4t + (ks * 64 + lane) * 8);
                bf16x8v a = *(const bf16x8v*)&A[p4 * NF + (kb ^ ((p4 & 7) << 3))];
                accf = __builtin_amdgcn_mfma_f32_16x16x32_bf16(w, a, accf, 0, 0, 0);
            }
            if (h == 0) { // D rows 0..2 = output channels
                Ostage[0 * BM + p4] = accf[0];
                Ostage[1 * BM + p4] = accf[1];
                Ostage[2 * BM + p4] = accf[2];
            }
        }
    }
    __syncthreads();

    // P9: residual + clip + full-cacheline stores (128 floats/channel contiguous)
    {
#pragma unroll
        for (int rep = 0; rep < 2; ++rep) {
            int t = tid + rep * 256;
            if (t < 3 * BM) {
                int c = t >> 7, p = t & 127;
                float v = Ostage[c * BM + p] + x[xbase + (size_t)c * HW + p];
                out[xbase + (size_t)c * HW + p] = fminf(fmaxf(v, 0.f), 1.f);
            }
        }
    }
}

extern "C" void kernel_launch(void* const* d_in, const int* in_sizes, int n_in,
                              void* d_out, int out_size, void* d_ws, size_t ws_size,
                              hipStream_t stream) {
    const float* x     = (const float*)d_in[0];
    const float* style = (const float*)d_in[1];
    const float* W0    = (const float*)d_in[2];
    const float* b0    = (const float*)d_in[3];
    const float* W1    = (const float*)d_in[4];
    const float* b1    = (const float*)d_in[5];
    const float* W2    = (const float*)d_in[6];
    const float* b2    = (const float*)d_in[7];
    const float* W3    = (const float*)d_in[8];
    const float* b3    = (const float*)d_in[9];
    const float* W4    = (const float*)d_in[10];
    const float* b4    = (const float*)d_in[11];
    float* out = (float*)d_out;

    // ws layout: Wt (3*256*256 bf16, fragment-ordered) | W4t (16*256 bf16) | b0f
    u16*   Wt  = (u16*)d_ws;
    u16*   W4t = Wt + 3 * NF * NF;
    float* b0f = (float*)(W4t + 16 * NF);

    const int prep_threads = 3 * NF * NF + 16 * NF + NF;
    prep_kernel<<<(prep_threads + 255) / 256, 256, 0, stream>>>(
        W0, b0, style, W1, W2, W3, W4, Wt, W4t, b0f);

    main_kernel<<<NIMG * BLOCKS_PER_IMG, 256, 0, stream>>>(
        x, W0, b1, b2, b3, b4, Wt, W4t, b0f, out);
}